// Round 10
// baseline (53400.964 us; speedup 1.0000x reference)
//
#include <hip/hip_runtime.h>
#include <hip/hip_fp16.h>

// LSTM: B=64, T=2048, D=128, U=256.
// Phase 1: xz = inputs @ Wx (f32 tiled GEMM) -- R1/R3-proven, unchanged.
// Phase 2 (R10): R1-R8 all plateau at ~3.6us/step because of 256 broadcast
//   ds_read_b128 h-reads per CU per step (~12cyc each = ~3100cyc = the whole
//   step) -- the kernels were LDS-broadcast-bound, never weight-bound.
//   Fix 1: h pairs gathered once per wave (1 ds_read_b128, lane g holds pairs
//          4g..4g+3), then v_readlane -> SGPR -> v_dot2_f32_f16 src0.
//   Fix 2: split each batch's 1024 cols across 2 WGs (128 WGs, 512thr,
//          1 col/thread): 96 weight pairs in regs (fits proven 128 grant)
//          + 32 in LDS -> fully on-chip. Per-step z-exchange via parity
//          double-buffered global zpub + monotonic flags (agent scope).

#define NB 64
#define NT 2048
#define ND 128
#define NU 256
#define N4U 1024

typedef _Float16 f16;
typedef _Float16 f16x2 __attribute__((ext_vector_type(2)));
typedef float f32x4 __attribute__((ext_vector_type(4)));
typedef unsigned int u32;
typedef unsigned int u32x4 __attribute__((ext_vector_type(4)));

__device__ __forceinline__ float sigm(float x) { return 1.0f / (1.0f + __expf(-x)); }
__device__ __forceinline__ float tanh_(float x) { return 1.0f - 2.0f / (__expf(2.0f * x) + 1.0f); }

// ---------------- Phase 1: xz[b][t - t0][j] = sum_k X[b][t][k] * Wx[k][j] ----
__global__ __launch_bounds__(256) void xz_gemm(const float* __restrict__ X,
                                               const float* __restrict__ Wx,
                                               float* __restrict__ XZ,
                                               int t0, int tc) {
  __shared__ __align__(16) float xs[64][ND];
  __shared__ __align__(16) float ws[ND][64];
  const int tid = threadIdx.x;
  const int b = blockIdx.y;
  const int row0 = t0 + blockIdx.x * 64;
  const int col0 = blockIdx.z * 64;

  {
    const float* src = X + ((size_t)b * NT + row0) * ND;
#pragma unroll
    for (int ii = 0; ii < 8; ++ii) {
      int q = tid + 256 * ii;
      int r = q >> 5;
      int k4 = q & 31;
      f32x4 v = *(const f32x4*)(src + (size_t)r * ND + 4 * k4);
      *(f32x4*)&xs[r][4 * k4] = v;
    }
#pragma unroll
    for (int ii = 0; ii < 8; ++ii) {
      int q = tid + 256 * ii;
      int k = q >> 4;
      int c4 = q & 15;
      f32x4 v = *(const f32x4*)(Wx + (size_t)k * N4U + col0 + 4 * c4);
      *(f32x4*)&ws[k][4 * c4] = v;
    }
  }
  __syncthreads();

  const int tx = tid & 15, ty = tid >> 4;
  float acc[4][4];
#pragma unroll
  for (int i = 0; i < 4; ++i)
#pragma unroll
    for (int j = 0; j < 4; ++j) acc[i][j] = 0.0f;

#pragma unroll 8
  for (int k = 0; k < ND; ++k) {
    f32x4 bv = *(const f32x4*)&ws[k][4 * tx];
    float a0 = xs[4 * ty + 0][k];
    float a1 = xs[4 * ty + 1][k];
    float a2 = xs[4 * ty + 2][k];
    float a3 = xs[4 * ty + 3][k];
#pragma unroll
    for (int j = 0; j < 4; ++j) {
      acc[0][j] += a0 * bv[j];
      acc[1][j] += a1 * bv[j];
      acc[2][j] += a2 * bv[j];
      acc[3][j] += a3 * bv[j];
    }
  }

  float* dst = XZ + ((size_t)b * tc + (row0 - t0)) * N4U + col0;
#pragma unroll
  for (int i = 0; i < 4; ++i) {
    f32x4 v;
#pragma unroll
    for (int j = 0; j < 4; ++j) v[j] = acc[i][j];
    *(f32x4*)(dst + (size_t)(4 * ty + i) * N4U + 4 * tx) = v;
  }
}

// ---------------- Phase 2: paired-WG sequential scan -----------------------
// grid 128: wg = blockIdx.x, b = wg & 63, half = wg >> 6.
// 512 threads; thread t owns global column j = half*512 + t.

// one pair-dot: hp = pair (4*G+Q) of h, broadcast from lane G via readlane;
// dot2 consumes the SGPR directly as src0.
#define RLDOT(ACC, G, Q, WPAIR) do {                                        \
    u32 _hp;                                                                \
    asm("v_readlane_b32 %0, %1, %2" : "=s"(_hp) : "v"(vh[Q]), "i"(G));      \
    asm("v_dot2_f32_f16 %0, %1, %2, %0" : "+v"(ACC) : "s"(_hp), "v"(WPAIR));\
  } while (0)

#define ACCOF(G) ((G & 1) ? e0 : a0)
#define G4(G) do {                       \
    RLDOT(ACCOF(G), G, 0, wr[4 * G + 0]); \
    RLDOT(ACCOF(G), G, 1, wr[4 * G + 1]); \
    RLDOT(ACCOF(G), G, 2, wr[4 * G + 2]); \
    RLDOT(ACCOF(G), G, 3, wr[4 * G + 3]); \
  } while (0)
#define GL4(G, GL) do {                  \
    u32x4 wv = wl[GL][tid];              \
    RLDOT(ACCOF(G), G, 0, wv[0]);        \
    RLDOT(ACCOF(G), G, 1, wv[1]);        \
    RLDOT(ACCOF(G), G, 2, wv[2]);        \
    RLDOT(ACCOF(G), G, 3, wv[3]);        \
  } while (0)

#define PINU8(B_) asm volatile("" : "+v"(wr[B_]), "+v"(wr[B_+1]), "+v"(wr[B_+2]), \
                                    "+v"(wr[B_+3]), "+v"(wr[B_+4]), "+v"(wr[B_+5]), \
                                    "+v"(wr[B_+6]), "+v"(wr[B_+7]))

__global__ __launch_bounds__(512, 1) void lstm_split(
    const float* __restrict__ Wh, const float* __restrict__ bias,
    const float* __restrict__ XZ, float* __restrict__ out,
    float* __restrict__ state, float* __restrict__ zpub,
    int* __restrict__ flags, int t0, int tc) {
  __shared__ __align__(16) u32x4 wl[8][512];   // weight pairs 96..127 (64KB)
  __shared__ float zown[512];                  // own-half z           (2KB)
  __shared__ __align__(16) f16 hbuf[NU];       // h as f16             (512B)
  __shared__ char pad_[20480];                 // force 1 WG/CU (total >84KB)

  const int tid = threadIdx.x;
  const int lane = tid & 63;
  const int wg = blockIdx.x;
  const int b = wg & 63;
  const int half = wg >> 6;
  const int j = half * 512 + tid;
  if (tc < 0) pad_[tid] = 0;                   // keep pad alive

  const float bj = bias[j];

  // weight pairs 0..95 -> registers (as u32-packed f16x2)
  u32 wr[96];
#pragma unroll
  for (int p = 0; p < 96; ++p) {
    f16x2 w;
    w.x = (f16)Wh[(size_t)(2 * p) * N4U + j];
    w.y = (f16)Wh[(size_t)(2 * p + 1) * N4U + j];
    wr[p] = __builtin_bit_cast(u32, w);
  }
  // weight pairs 96..127 -> LDS
#pragma unroll
  for (int gl = 0; gl < 8; ++gl) {
    u32x4 w;
#pragma unroll
    for (int q2 = 0; q2 < 4; ++q2) {
      int p = 96 + 4 * gl + q2;
      f16x2 t2;
      t2.x = (f16)Wh[(size_t)(2 * p) * N4U + j];
      t2.y = (f16)Wh[(size_t)(2 * p + 1) * N4U + j];
      w[q2] = __builtin_bit_cast(u32, t2);
    }
    wl[gl][tid] = w;
  }

  float creg = 0.0f, hreg = 0.0f;
  if (tid < NU) {
    if (t0 != 0) {
      hreg = state[(size_t)b * 2 * NU + tid];
      creg = state[(size_t)b * 2 * NU + NU + tid];
    }
    hbuf[tid] = (f16)hreg;
  }
  __syncthreads();

  const float* xzp = XZ + (size_t)b * tc * N4U + j;
  float xf = xzp[0];

  for (int s = 0; s < tc; ++s) {
    const int gstep = t0 + s + 1;
    const int par = (t0 + s) & 1;

    // pin weight regs (free when resident)
    PINU8(0); PINU8(8); PINU8(16); PINU8(24); PINU8(32); PINU8(40);
    PINU8(48); PINU8(56); PINU8(64); PINU8(72); PINU8(80); PINU8(88);

    // gather h: lane g (0..31) holds pairs 4g..4g+3 (one b128 per wave)
    u32x4 vh = *(const u32x4*)((const char*)hbuf + (size_t)(lane & 31) * 16);

    float a0 = xf + bj, e0 = 0.0f;
    G4(0);  G4(1);  G4(2);  G4(3);  G4(4);  G4(5);  G4(6);  G4(7);
    G4(8);  G4(9);  G4(10); G4(11); G4(12); G4(13); G4(14); G4(15);
    G4(16); G4(17); G4(18); G4(19); G4(20); G4(21); G4(22); G4(23);
    GL4(24, 0); GL4(25, 1); GL4(26, 2); GL4(27, 3);
    GL4(28, 4); GL4(29, 5); GL4(30, 6); GL4(31, 7);
    float z = a0 + e0;

    zown[tid] = z;
    zpub[((size_t)par * NB + b) * N4U + j] = z;
    __threadfence();          // agent-scope: publish before flag
    __syncthreads();          // all 512 stores fenced
    if (tid == 0)
      __hip_atomic_store(&flags[wg], gstep, __ATOMIC_RELEASE,
                         __HIP_MEMORY_SCOPE_AGENT);

    if (s + 1 < tc) xf = xzp[(size_t)(s + 1) * N4U];  // prefetch during spin

    if (tid < NU) {
      const int* pf = &flags[wg ^ 64];
      int v;
      long guard = 0;
      do {
        v = __hip_atomic_load(pf, __ATOMIC_ACQUIRE, __HIP_MEMORY_SCOPE_AGENT);
      } while (v < gstep && ++guard < 200000000L);

      float zi, zf_, zg, zo;
      const float* zp = zpub + ((size_t)par * NB + b) * N4U;
      if (half == 0) {
        zi = zown[tid];       zf_ = zown[tid + 256];
        zg = zp[512 + tid];   zo  = zp[768 + tid];
      } else {
        zg = zown[tid];       zo  = zown[tid + 256];
        zi = zp[tid];         zf_ = zp[256 + tid];
      }
      float ig = sigm(zi), fg = sigm(zf_), og = sigm(zo), gg = tanh_(zg);
      creg = fg * creg + ig * gg;
      hreg = og * tanh_(creg);
      if (half == 0) out[((size_t)b * NT + t0 + s) * NU + tid] = hreg;
      hbuf[tid] = (f16)hreg;
    }
    __syncthreads();
  }

  if (tid < NU && half == 0) {
    state[(size_t)b * 2 * NU + tid] = hreg;
    state[(size_t)b * 2 * NU + NU + tid] = creg;
  }
}

extern "C" void kernel_launch(void* const* d_in, const int* in_sizes, int n_in,
                              void* d_out, int out_size, void* d_ws, size_t ws_size,
                              hipStream_t stream) {
  const float* inputs = (const float*)d_in[0];  // [64,2048,128]
  const float* Wx     = (const float*)d_in[1];  // [128,1024]
  const float* Wh     = (const float*)d_in[2];  // [256,1024]
  const float* bias   = (const float*)d_in[3];  // [1024]
  float* out = (float*)d_out;                   // [64,2048,256]

  // workspace layout
  char* wsp = (char*)d_ws;
  int*   flags = (int*)wsp;                              // 128 ints (4KB pad)
  float* zpub  = (float*)(wsp + 4096);                   // 2*64*1024*4 = 512KB
  float* state = (float*)(wsp + 4096 + 524288);          // 128KB
  float* xzbuf = (float*)(wsp + 4096 + 524288 + 131072);
  const size_t head = 4096 + 524288 + 131072;

  (void)hipMemsetAsync(flags, 0, 4096, stream);          // flags start at 0

  size_t avail = (ws_size > head) ? (ws_size - head) : 0;
  size_t step_bytes = (size_t)NB * N4U * sizeof(float);  // 256KB per timestep
  long tc_l = (long)(avail / step_bytes);
  int tc = (tc_l > NT) ? NT : (int)tc_l;
  tc = (tc / 64) * 64;
  if (tc < 64) tc = 64;

  for (int t0 = 0; t0 < NT; t0 += tc) {
    int cur = NT - t0;
    if (cur > tc) cur = tc;
    dim3 g1(cur >> 6, NB, 16);
    xz_gemm<<<g1, 256, 0, stream>>>(inputs, Wx, xzbuf, t0, cur);
    lstm_split<<<128, 512, 0, stream>>>(Wh, bias, xzbuf, out, state,
                                        zpub, flags, t0, cur);
  }
}

// Round 11
// 24701.382 us; speedup vs baseline: 2.1619x; 2.1619x over previous
//
#include <hip/hip_runtime.h>
#include <hip/hip_fp16.h>

// LSTM: B=64, T=2048, D=128, U=256.
// Phase 1: xz = inputs @ Wx (f32 tiled GEMM) -- R1/R3-proven, unchanged.
// Phase 2 (R11): R9's correctness-verified MFMA core (uniform-A h trick,
//   load_btile B-mapping, C col=lane&15 extraction), re-budgeted to the
//   PROVEN register grants (512thr: arch=128, acc=128):
//     64 B-tiles/wave = 32 AGPR (128 acc, exact) + 14 VGPR (56 arch)
//                       + 18 LDS (147KB static, R8-proven block size).
//   MFMA reads B natively from AGPR -> no accvgpr_read tax (R7's bug) and
//   demand <= grant -> in-loop pins are free (R9's bug was pins on
//   over-budget spilled values). One WG per batch: no cross-CU sync (R10).

#define NB 64
#define NT 2048
#define ND 128
#define NU 256
#define N4U 1024

#define QA 32            // q < 32           -> AGPR tiles (128 acc regs)
#define QV 46            // 32 <= q < 46     -> arch VGPR tiles (14 = 56 regs)
#define NLDS (64 - QV)   // q >= 46          -> LDS tiles (18 = 147KB)

typedef _Float16 f16;
typedef _Float16 f16x8 __attribute__((ext_vector_type(8)));
typedef float f32x4 __attribute__((ext_vector_type(4)));

__device__ __forceinline__ float sigm(float x) { return 1.0f / (1.0f + __expf(-x)); }
__device__ __forceinline__ float tanh_(float x) { return 1.0f - 2.0f / (__expf(2.0f * x) + 1.0f); }

// ---------------- Phase 1: xz[b][t - t0][j] = sum_k X[b][t][k] * Wx[k][j] ----
__global__ __launch_bounds__(256) void xz_gemm(const float* __restrict__ X,
                                               const float* __restrict__ Wx,
                                               float* __restrict__ XZ,
                                               int t0, int tc) {
  __shared__ __align__(16) float xs[64][ND];
  __shared__ __align__(16) float ws[ND][64];
  const int tid = threadIdx.x;
  const int b = blockIdx.y;
  const int row0 = t0 + blockIdx.x * 64;
  const int col0 = blockIdx.z * 64;

  {
    const float* src = X + ((size_t)b * NT + row0) * ND;
#pragma unroll
    for (int ii = 0; ii < 8; ++ii) {
      int q = tid + 256 * ii;
      int r = q >> 5;
      int k4 = q & 31;
      f32x4 v = *(const f32x4*)(src + (size_t)r * ND + 4 * k4);
      *(f32x4*)&xs[r][4 * k4] = v;
    }
#pragma unroll
    for (int ii = 0; ii < 8; ++ii) {
      int q = tid + 256 * ii;
      int k = q >> 4;
      int c4 = q & 15;
      f32x4 v = *(const f32x4*)(Wx + (size_t)k * N4U + col0 + 4 * c4);
      *(f32x4*)&ws[k][4 * c4] = v;
    }
  }
  __syncthreads();

  const int tx = tid & 15, ty = tid >> 4;
  float acc[4][4];
#pragma unroll
  for (int i = 0; i < 4; ++i)
#pragma unroll
    for (int j = 0; j < 4; ++j) acc[i][j] = 0.0f;

#pragma unroll 8
  for (int k = 0; k < ND; ++k) {
    f32x4 bv = *(const f32x4*)&ws[k][4 * tx];
    float a0 = xs[4 * ty + 0][k];
    float a1 = xs[4 * ty + 1][k];
    float a2 = xs[4 * ty + 2][k];
    float a3 = xs[4 * ty + 3][k];
#pragma unroll
    for (int j = 0; j < 4; ++j) {
      acc[0][j] += a0 * bv[j];
      acc[1][j] += a1 * bv[j];
      acc[2][j] += a2 * bv[j];
      acc[3][j] += a3 * bv[j];
    }
  }

  float* dst = XZ + ((size_t)b * tc + (row0 - t0)) * N4U + col0;
#pragma unroll
  for (int i = 0; i < 4; ++i) {
    f32x4 v;
#pragma unroll
    for (int j = 0; j < 4; ++j) v[j] = acc[i][j];
    *(f32x4*)(dst + (size_t)(4 * ty + i) * N4U + 4 * tx) = v;
  }
}

// ---------------- Phase 2: MFMA sequential scan, one WG per batch -----------

// B-tile (ng, kt): element e = Wh[kt*32 + (lane>>4)*8 + e][ng*16 + (lane&15)]
// (R9-verified mapping: pairs with uniform-A h slices, dot over k invariant.)
__device__ __forceinline__ f16x8 load_btile(const float* __restrict__ Wh,
                                            int ng, int kt, int lane) {
  const int col = ng * 16 + (lane & 15);
  const int kb = kt * 32 + ((lane >> 4) << 3);
  f16x8 w;
#pragma unroll
  for (int e = 0; e < 8; ++e)
    w[e] = (f16)Wh[(size_t)(kb + e) * N4U + col];
  return w;
}

#define PA8(i) asm volatile("" : "+a"(ba[i]), "+a"(ba[i+1]), "+a"(ba[i+2]), \
                                 "+a"(ba[i+3]), "+a"(ba[i+4]), "+a"(ba[i+5]), \
                                 "+a"(ba[i+6]), "+a"(ba[i+7]))
#define PV7(i) asm volatile("" : "+v"(bv[i]), "+v"(bv[i+1]), "+v"(bv[i+2]), \
                                 "+v"(bv[i+3]), "+v"(bv[i+4]), "+v"(bv[i+5]), \
                                 "+v"(bv[i+6]))

__global__ __launch_bounds__(512, 1) void lstm_seq(const float* __restrict__ Wh,
                                                   const float* __restrict__ bias,
                                                   const float* __restrict__ XZ,
                                                   float* __restrict__ out,
                                                   float* __restrict__ state,
                                                   int t0, int tc) {
  __shared__ __align__(16) f16x8 wlds[NLDS][512];  // 147456 B
  __shared__ float zbuf[N4U];                      // 4096 B
  __shared__ __align__(16) f16 hbuf[NU];           // 512 B  (total 152064)

  const int tid = threadIdx.x;
  const int lane = tid & 63;
  const int wave = tid >> 6;
  const int b = blockIdx.x;

  // ---- B-tile residency: q = kt*8 + nl, ng = wave*8 + nl ----
  f16x8 ba[QA];                                    // AGPR tiles (128 acc)
#pragma unroll
  for (int q = 0; q < QA; ++q)
    ba[q] = load_btile(Wh, wave * 8 + (q & 7), q >> 3, lane);
  PA8(0); PA8(8); PA8(16); PA8(24);                // set AGPR class (once)

  f16x8 bv[QV - QA];                               // VGPR tiles (56 arch)
#pragma unroll
  for (int q = QA; q < QV; ++q)
    bv[q - QA] = load_btile(Wh, wave * 8 + (q & 7), q >> 3, lane);

#pragma unroll
  for (int q = QV; q < 64; ++q)                    // LDS tiles
    wlds[q - QV][tid] = load_btile(Wh, wave * 8 + (q & 7), q >> 3, lane);

  // ---- gate-thread setup (threads 0..255) ----
  float b0 = 0.f, b1 = 0.f, b2 = 0.f, b3 = 0.f;
  float creg = 0.0f, hreg = 0.0f;
  if (tid < NU) {
    b0 = bias[tid];
    b1 = bias[tid + 256];
    b2 = bias[tid + 512];
    b3 = bias[tid + 768];
    if (t0 != 0) {
      hreg = state[(size_t)b * 2 * NU + tid];
      creg = state[(size_t)b * 2 * NU + NU + tid];
    }
    hbuf[tid] = (f16)hreg;
  }
  __syncthreads();

  const float* xzp = XZ + (size_t)b * tc * N4U;
  float x0 = 0.f, x1 = 0.f, x2 = 0.f, x3 = 0.f;
  if (tid < NU) {
    x0 = xzp[tid];
    x1 = xzp[tid + 256];
    x2 = xzp[tid + 512];
    x3 = xzp[tid + 768];
  }

  const f32x4 ZERO4 = {0.f, 0.f, 0.f, 0.f};

  for (int s = 0; s < tc; ++s) {
    // keep classes pinned; demand <= grant so these compile to nothing
    PA8(0); PA8(8); PA8(16); PA8(24);
    PV7(0); PV7(7);

    f32x4 ca[8];
#pragma unroll
    for (int n = 0; n < 8; ++n) ca[n] = ZERO4;

    const f16x8* hb = (const f16x8*)hbuf;
#pragma unroll
    for (int kt = 0; kt < 8; ++kt) {
      f16x8 a = hb[kt * 4 + (lane >> 4)];   // uniform per 16-lane group
#pragma unroll
      for (int n = 0; n < 8; ++n) {
        const int q = kt * 8 + n;
        f16x8 bb;
        if (q < QA)       bb = ba[q];
        else if (q < QV)  bb = bv[q - QA];
        else              bb = wlds[q - QV][tid];
        ca[n] = __builtin_amdgcn_mfma_f32_16x16x32_f16(a, bb, ca[n], 0, 0, 0);
      }
    }

    if (lane < 16) {
#pragma unroll
      for (int n = 0; n < 8; ++n)
        zbuf[(wave * 8 + n) * 16 + lane] = ca[n][0];   // C col = lane&15
    }
    __syncthreads();   // zbuf ready; all A-reads of hbuf done

    if (tid < NU) {
      float zi = zbuf[tid]       + x0 + b0;
      float zf = zbuf[tid + 256] + x1 + b1;
      float zg = zbuf[tid + 512] + x2 + b2;
      float zo = zbuf[tid + 768] + x3 + b3;
      if (s + 1 < tc) {
        const float* xn = xzp + (size_t)(s + 1) * N4U;
        x0 = xn[tid];
        x1 = xn[tid + 256];
        x2 = xn[tid + 512];
        x3 = xn[tid + 768];
      }
      float ig = sigm(zi), fg = sigm(zf), og = sigm(zo), gg = tanh_(zg);
      creg = fg * creg + ig * gg;
      hreg = og * tanh_(creg);
      out[((size_t)b * NT + t0 + s) * NU + tid] = hreg;
      hbuf[tid] = (f16)hreg;
    }
    __syncthreads();   // hbuf ready for s+1
  }

  if (tid < NU) {
    state[(size_t)b * 2 * NU + tid] = hreg;
    state[(size_t)b * 2 * NU + NU + tid] = creg;
  }
}

extern "C" void kernel_launch(void* const* d_in, const int* in_sizes, int n_in,
                              void* d_out, int out_size, void* d_ws, size_t ws_size,
                              hipStream_t stream) {
  const float* inputs = (const float*)d_in[0];  // [64,2048,128]
  const float* Wx     = (const float*)d_in[1];  // [128,1024]
  const float* Wh     = (const float*)d_in[2];  // [256,1024]
  const float* bias   = (const float*)d_in[3];  // [1024]
  float* out = (float*)d_out;                   // [64,2048,256]

  const size_t state_bytes = (size_t)NB * 2 * NU * sizeof(float);  // 128KB
  float* state = (float*)d_ws;
  float* xzbuf = (float*)((char*)d_ws + state_bytes);

  size_t avail = (ws_size > state_bytes) ? (ws_size - state_bytes) : 0;
  size_t step_bytes = (size_t)NB * N4U * sizeof(float);  // 256KB per timestep
  long tc_l = (long)(avail / step_bytes);
  int tc = (tc_l > NT) ? NT : (int)tc_l;
  tc = (tc / 64) * 64;
  if (tc < 64) tc = 64;

  for (int t0 = 0; t0 < NT; t0 += tc) {
    int cur = NT - t0;
    if (cur > tc) cur = tc;
    dim3 g1(cur >> 6, NB, 16);
    xz_gemm<<<g1, 256, 0, stream>>>(inputs, Wx, xzbuf, t0, cur);
    lstm_seq<<<NB, 512, 0, stream>>>(Wh, bias, xzbuf, out, state, t0, cur);
  }
}